// Round 3
// baseline (4315.905 us; speedup 1.0000x reference)
//
#include <hip/hip_runtime.h>
#include <math.h>

// dims (hardcoded per reference)
#define T_STEPS 50
#define BB 4   // batch rows per block; grid = 2048/4 = 512 blocks -> 2 blocks/CU

// ws float offsets (total 299008 floats = 1.196 MB)
#define OFF_WCT   0          // [6][192][64]  (Wv@W_ih)^T per rim
#define OFF_WHHT  73728      // [6][192][64]  Whh^T
#define OFF_WQT   147456     // [6][64][64]   Wq^T
#define OFF_WKT   172032     // [64][64]      Wk^T
#define OFF_WQCT  176128     // [6][128][64]  Wqc^T
#define OFF_WKCT  225280     // [6][128][64]  Wkc^T
#define OFF_WVCT  274432     // [6][64][64]   Wvc^T

__device__ __forceinline__ void fma4(float4& a, const float4 v, const float s) {
  a.x = fmaf(v.x, s, a.x); a.y = fmaf(v.y, s, a.y);
  a.z = fmaf(v.z, s, a.z); a.w = fmaf(v.w, s, a.w);
}
__device__ __forceinline__ float sigmoidf_(float x) { return 1.0f / (1.0f + __expf(-x)); }
__device__ __forceinline__ float tanhf_(float x) {
  float ax = fabsf(x);
  float e = __expf(-2.0f * ax);
  float t = (1.0f - e) / (1.0f + e);
  return copysignf(t, x);
}

// WcT[r][g][f] = sum_v Wv[f][v] * Wih[r][v][g]   (Wcomb = Wv@W_ih, stored transposed)
__global__ void wcombT_kernel(const float* __restrict__ Wv, const float* __restrict__ Wih,
                              float* __restrict__ ws) {
  int f = threadIdx.x;          // 0..63
  int g = blockIdx.x % 192;
  int r = blockIdx.x / 192;
  float acc = 0.f;
#pragma unroll 8
  for (int v = 0; v < 128; ++v)
    acc = fmaf(Wv[f * 128 + v], Wih[(r * 128 + v) * 192 + g], acc);
  ws[OFF_WCT + (r * 192 + g) * 64 + f] = acc;
}

// transpose the remaining weight matrices into ws ([outcol][k] layouts)
__global__ void prep_transpose(const float* __restrict__ Whh, const float* __restrict__ Wq,
                               const float* __restrict__ Wk, const float* __restrict__ Wqc,
                               const float* __restrict__ Wkc, const float* __restrict__ Wvc,
                               float* __restrict__ ws) {
  int i = blockIdx.x * 256 + threadIdx.x;
  if (i < 73728) {                       // WhhT[r][g][h] = Whh[r][h][g]
    int r = i / 12288, rem = i % 12288, g = rem / 64, h2 = rem % 64;
    ws[OFF_WHHT + i] = Whh[(r * 64 + h2) * 192 + g];
  } else if (i < 98304) {                // WqT[r][k][h] = Wq[r][h][k]
    int j = i - 73728;
    int r = j / 4096, rem = j % 4096, k = rem / 64, h2 = rem % 64;
    ws[OFF_WQT + j] = Wq[(r * 64 + h2) * 64 + k];
  } else if (i < 102400) {               // WkT[k][f] = Wk[f][k]
    int j = i - 98304;
    int k = j / 64, f = j % 64;
    ws[OFF_WKT + j] = Wk[f * 64 + k];
  } else if (i < 151552) {               // WqcT[r][g][h] = Wqc[r][h][g]
    int j = i - 102400;
    int r = j / 8192, rem = j % 8192, g = rem / 64, h2 = rem % 64;
    ws[OFF_WQCT + j] = Wqc[(r * 64 + h2) * 128 + g];
  } else if (i < 200704) {               // WkcT
    int j = i - 151552;
    int r = j / 8192, rem = j % 8192, g = rem / 64, h2 = rem % 64;
    ws[OFF_WKCT + j] = Wkc[(r * 64 + h2) * 128 + g];
  } else if (i < 225280) {               // WvcT[r][g][h] = Wvc[r][h][g]
    int j = i - 200704;
    int r = j / 4096, rem = j % 4096, g = rem / 64, h2 = rem % 64;
    ws[OFF_WVCT + j] = Wvc[(r * 64 + h2) * 64 + g];
  }
}

// NOTE: __launch_bounds__ arg2 empirically behaves as min BLOCKS/CU on this
// toolchain (round-2: (512,4) -> 64-VGPR cap -> spills). (512,2) -> 128 cap.
__global__ __launch_bounds__(512, 2) void rims_kernel(
    const float* __restrict__ x, const float* __restrict__ statics,
    const float* __restrict__ maskp, const float* __restrict__ delta,
    const float* __restrict__ xlast, const float* __restrict__ xmean,
    const float* __restrict__ wdgp, const float* __restrict__ bdgp,
    const float* __restrict__ bih, const float* __restrict__ bhh,
    const float* __restrict__ W1, const float* __restrict__ b1,
    const float* __restrict__ W2, const float* __restrict__ b2,
    const float* __restrict__ ws, float* __restrict__ out) {
  // transposed activation tiles (b128 broadcast reads in GEMMs; rows 16B-aligned)
  __shared__ float xh_T[64][4];
  __shared__ float h_T[6][64][4];
  __shared__ float hn_T[6][64][4];
  // GEMM outputs, row-major [..][bb][col]: lane-consecutive read & write -> conflict-free
  __shared__ float K0_R[4][64];
  __shared__ float Q_R[6][4][64];
  __shared__ float qc_R[6][4][128];
  __shared__ float kc_R[6][4][128];
  __shared__ float vc_R[6][4][64];
  __shared__ float p0_l[4][6];
  __shared__ float act_l[4][6];

  const int tid = threadIdx.x;
  const int wave = tid >> 6;   // 0..7
  const int lane = tid & 63;
  const int b0 = blockIdx.x * BB;

  for (int i = tid; i < 6 * 64 * 4; i += 512) (&h_T[0][0][0])[i] = 0.f;

  const float wdg = wdgp[lane];
  const float bdg = bdgp[lane];
  const float xmv = xmean[(size_t)(b0 + (wave & 3)) * 64 + lane];
  // GRU biases: hoisted to registers for the wave that owns rim r = wave
  float bir = 0.f, biz = 0.f, bin = 0.f, bhr = 0.f, bhz = 0.f, bhn = 0.f;
  if (wave < 6) {
    bir = bih[wave * 192 + lane]; biz = bih[wave * 192 + 64 + lane];
    bin = bih[wave * 192 + 128 + lane];
    bhr = bhh[wave * 192 + lane]; bhz = bhh[wave * 192 + 64 + lane];
    bhn = bhh[wave * 192 + 128 + lane];
  }
  __syncthreads();

  for (int t = 0; t < T_STEPS; ++t) {
    // ---------------- X: GRU-D decay / imputation (waves 0..3; thread=(bb=wave, feat=lane))
    if (wave < 4) {
      size_t off = ((size_t)(b0 + wave) * T_STEPS + t) * 64 + lane;
      float xt = x[off], mt = maskp[off], dt = delta[off], xl = xlast[off];
      float gm = __expf(-fmaxf(fmaf(dt, wdg, bdg), 0.f));
      xh_T[lane][wave] = mt * xt + (1.f - mt) * (gm * xl + (1.f - gm) * xmv);
    }
    __syncthreads();
    // ---------------- G0: K0 = xh@Wk (wave 0), Q[r] = h[r]@Wq[r] (waves 1..6)
    if (wave < 7) {
      const float* WT = (wave == 0) ? (ws + OFF_WKT) : (ws + OFF_WQT + (wave - 1) * 4096);
      const float(*srcT)[4] = (wave == 0) ? xh_T : h_T[wave - 1];
      float4 acc = {0, 0, 0, 0};
#pragma unroll 4
      for (int kk = 0; kk < 16; ++kk) {
        float4 wv = *(const float4*)(WT + lane * 64 + kk * 4);
        float4 a0 = *(const float4*)&srcT[kk * 4 + 0][0];
        float4 a1 = *(const float4*)&srcT[kk * 4 + 1][0];
        float4 a2 = *(const float4*)&srcT[kk * 4 + 2][0];
        float4 a3 = *(const float4*)&srcT[kk * 4 + 3][0];
        fma4(acc, a0, wv.x); fma4(acc, a1, wv.y); fma4(acc, a2, wv.z); fma4(acc, a3, wv.w);
      }
      if (wave == 0) {
        K0_R[0][lane] = acc.x; K0_R[1][lane] = acc.y;
        K0_R[2][lane] = acc.z; K0_R[3][lane] = acc.w;
      } else {
        float* q = &Q_R[wave - 1][0][0];
        q[lane] = acc.x; q[64 + lane] = acc.y; q[128 + lane] = acc.z; q[192 + lane] = acc.w;
      }
    }
    __syncthreads();
    // ---------------- R: logits, p0 = sigmoid(logit), top-4 mask (waves 0..3, bb=wave)
    if (wave < 4) {
      const int bb = wave;
      float k0 = K0_R[bb][lane];
      float logit[6];
#pragma unroll
      for (int r = 0; r < 6; ++r) {
        float p = Q_R[r][bb][lane] * k0;
#pragma unroll
        for (int d = 1; d < 64; d <<= 1) p += __shfl_xor(p, d, 64);
        logit[r] = p * 0.125f;  // 1/sqrt(KS)
      }
      if (lane == 0) {
#pragma unroll
        for (int r = 0; r < 6; ++r) {
          int rank = 0;
#pragma unroll
          for (int r2 = 0; r2 < 6; ++r2)
            rank += (logit[r2] > logit[r]) || (logit[r2] == logit[r] && r2 < r);
          p0_l[bb][r] = sigmoidf_(logit[r]);   // softmax([l,0])[0]
          act_l[bb][r] = (rank < 4) ? 1.f : 0.f;
        }
      }
    }
    __syncthreads();
    // ---------------- G1: fused gates + GRU pointwise; wave r handles rim r
    if (wave < 6) {
      const int r = wave;
      const float* WcT = ws + OFF_WCT + r * 12288;
      const float* WhT = ws + OFF_WHHT + r * 12288;
      float4 ua = {0,0,0,0}, ub = {0,0,0,0}, uc = {0,0,0,0};
      float4 ga = {0,0,0,0}, gb = {0,0,0,0}, gc = {0,0,0,0};
#pragma unroll 2
      for (int kk = 0; kk < 16; ++kk) {
        float4 w0 = *(const float4*)(WcT + lane * 64 + kk * 4);
        float4 w1 = *(const float4*)(WcT + (lane + 64) * 64 + kk * 4);
        float4 w2 = *(const float4*)(WcT + (lane + 128) * 64 + kk * 4);
        float4 v0 = *(const float4*)(WhT + lane * 64 + kk * 4);
        float4 v1 = *(const float4*)(WhT + (lane + 64) * 64 + kk * 4);
        float4 v2 = *(const float4*)(WhT + (lane + 128) * 64 + kk * 4);
#define G1J(J, W0C, W1C, W2C, V0C, V1C, V2C)                      \
        {                                                          \
          float4 xv = *(const float4*)&xh_T[kk * 4 + J][0];        \
          float4 hv = *(const float4*)&h_T[r][kk * 4 + J][0];      \
          fma4(ua, xv, W0C); fma4(ub, xv, W1C); fma4(uc, xv, W2C); \
          fma4(ga, hv, V0C); fma4(gb, hv, V1C); fma4(gc, hv, V2C); \
        }
        G1J(0, w0.x, w1.x, w2.x, v0.x, v1.x, v2.x)
        G1J(1, w0.y, w1.y, w2.y, v0.y, v1.y, v2.y)
        G1J(2, w0.z, w1.z, w2.z, v0.z, v1.z, v2.z)
        G1J(3, w0.w, w1.w, w2.w, v0.w, v1.w, v2.w)
#undef G1J
      }
      float4 hold = *(const float4*)&h_T[r][lane][0];
      auto gru1 = [&](float p0v, float u0, float u1, float u2, float g0, float g1,
                      float g2, float holdv) -> float {
        float rg = sigmoidf_(fmaf(p0v, u0, bir) + g0 + bhr);
        float zg = sigmoidf_(fmaf(p0v, u1, biz) + g1 + bhz);
        float ng = tanhf_(fmaf(p0v, u2, bin) + rg * (g2 + bhn));
        return (1.f - zg) * ng + zg * holdv;
      };
      float4 hn;
      hn.x = gru1(p0_l[0][r], ua.x, ub.x, uc.x, ga.x, gb.x, gc.x, hold.x);
      hn.y = gru1(p0_l[1][r], ua.y, ub.y, uc.y, ga.y, gb.y, gc.y, hold.y);
      hn.z = gru1(p0_l[2][r], ua.z, ub.z, uc.z, ga.z, gb.z, gc.z, hold.z);
      hn.w = gru1(p0_l[3][r], ua.w, ub.w, uc.w, ga.w, gb.w, gc.w, hold.w);
      *(float4*)&hn_T[r][lane][0] = hn;
    }
    __syncthreads();
    // ---------------- C1: comm projections qc/kc (units 0..11), vc pairs (12..14)
    for (int uu = wave; uu < 15; uu += 8) {
      if (uu < 12) {
        const int r = (uu < 6) ? uu : (uu - 6);
        const float* WT = ws + ((uu < 6) ? OFF_WQCT : OFF_WKCT) + r * 8192;
        float4 a0 = {0,0,0,0}, a1 = {0,0,0,0};
#pragma unroll 4
        for (int kk = 0; kk < 16; ++kk) {
          float4 w0 = *(const float4*)(WT + lane * 64 + kk * 4);
          float4 w1 = *(const float4*)(WT + (lane + 64) * 64 + kk * 4);
#define C1J(J, W0C, W1C)                                      \
          {                                                    \
            float4 xv = *(const float4*)&hn_T[r][kk * 4 + J][0]; \
            fma4(a0, xv, W0C); fma4(a1, xv, W1C);              \
          }
          C1J(0, w0.x, w1.x) C1J(1, w0.y, w1.y) C1J(2, w0.z, w1.z) C1J(3, w0.w, w1.w)
#undef C1J
        }
        float* dst = (uu < 6) ? &qc_R[r][0][0] : &kc_R[r][0][0];
        dst[0 * 128 + lane] = a0.x; dst[1 * 128 + lane] = a0.y;
        dst[2 * 128 + lane] = a0.z; dst[3 * 128 + lane] = a0.w;
        dst[0 * 128 + 64 + lane] = a1.x; dst[1 * 128 + 64 + lane] = a1.y;
        dst[2 * 128 + 64 + lane] = a1.z; dst[3 * 128 + 64 + lane] = a1.w;
      } else {
        const int rA = (uu - 12) * 2, rB = rA + 1;
        const float* WT = ws + OFF_WVCT;
        float4 a0 = {0,0,0,0}, a1 = {0,0,0,0};
#pragma unroll 4
        for (int kk = 0; kk < 16; ++kk) {
          float4 w0 = *(const float4*)(WT + (rA * 64 + lane) * 64 + kk * 4);
          float4 w1 = *(const float4*)(WT + (rB * 64 + lane) * 64 + kk * 4);
#define C1V(J, W0C, W1C)                                        \
          {                                                      \
            float4 xa = *(const float4*)&hn_T[rA][kk * 4 + J][0]; \
            float4 xb = *(const float4*)&hn_T[rB][kk * 4 + J][0]; \
            fma4(a0, xa, W0C); fma4(a1, xb, W1C);                \
          }
          C1V(0, w0.x, w1.x) C1V(1, w0.y, w1.y) C1V(2, w0.z, w1.z) C1V(3, w0.w, w1.w)
#undef C1V
        }
        vc_R[rA][0][lane] = a0.x; vc_R[rA][1][lane] = a0.y;
        vc_R[rA][2][lane] = a0.z; vc_R[rA][3][lane] = a0.w;
        vc_R[rB][0][lane] = a1.x; vc_R[rB][1][lane] = a1.y;
        vc_R[rB][2][lane] = a1.z; vc_R[rB][3][lane] = a1.w;
      }
    }
    __syncthreads();
    // ---------------- C2: comm attention + state update (wave = (bb, rim-half))
    {
      const int bb = wave >> 1;
      const int half = wave & 1;
      float kcA[6], kcB[6], vcv[6];
#pragma unroll
      for (int s = 0; s < 6; ++s) {
        kcA[s] = kc_R[s][bb][lane];
        kcB[s] = kc_R[s][bb][64 + lane];
        vcv[s] = vc_R[s][bb][lane];
      }
      const int cOut = lane >> 4;            // output head for this lane's comm col
      const int srcLane = (cOut & 1) << 5;   // lane holding that head's reduced score
      const float inv_sq = 0.17677669529663687f;  // 1/sqrt(QC)
#pragma unroll
      for (int jr = 0; jr < 3; ++jr) {
        const int rr = half * 3 + jr;
        float qA = qc_R[rr][bb][lane], qB = qc_R[rr][bb][64 + lane];
        float sL[6], sH[6];
#pragma unroll
        for (int s = 0; s < 6; ++s) {
          float p = qA * kcA[s];
          p += __shfl_xor(p, 1, 64); p += __shfl_xor(p, 2, 64); p += __shfl_xor(p, 4, 64);
          p += __shfl_xor(p, 8, 64); p += __shfl_xor(p, 16, 64);
          sL[s] = p * inv_sq;   // head 0 (lanes 0-31) / head 1 (lanes 32-63)
          float q = qB * kcB[s];
          q += __shfl_xor(q, 1, 64); q += __shfl_xor(q, 2, 64); q += __shfl_xor(q, 4, 64);
          q += __shfl_xor(q, 8, 64); q += __shfl_xor(q, 16, 64);
          sH[s] = q * inv_sq;   // heads 2 / 3
        }
        float mL = sL[0], mH = sH[0];
#pragma unroll
        for (int s = 1; s < 6; ++s) { mL = fmaxf(mL, sL[s]); mH = fmaxf(mH, sH[s]); }
        float sumL = 0.f, sumH = 0.f;
#pragma unroll
        for (int s = 0; s < 6; ++s) {
          sL[s] = __expf(sL[s] - mL); sumL += sL[s];
          sH[s] = __expf(sH[s] - mH); sumH += sH[s];
        }
        float rLn = 1.f / sumL, rHn = 1.f / sumH;
        float comm = 0.f;
#pragma unroll
        for (int s = 0; s < 6; ++s) {
          float tL = __shfl(sL[s] * rLn, srcLane, 64);
          float tH = __shfl(sH[s] * rHn, srcLane, 64);
          float cp = (cOut < 2) ? tL : tH;
          comm = fmaf(cp, vcv[s], comm);
        }
        float mk = act_l[bb][rr];
        float hnv = hn_T[rr][lane][bb];
        float hov = h_T[rr][lane][bb];
        h_T[rr][lane][bb] = (mk > 0.5f) ? (hnv + comm) : hov;
      }
    }
    __syncthreads();
  }  // t

  // ---------------- final MLP head (waves 0..3, bb = wave)
  if (wave < 4) {
    const int b = b0 + wave;
    float acc[10];
#pragma unroll
    for (int o = 0; o < 10; ++o) acc[o] = 0.f;
#pragma unroll
    for (int ii = 0; ii < 6; ++ii) {
      float f = h_T[ii][lane][wave];
      const float* w = W1 + (ii * 64 + lane) * 10;
#pragma unroll
      for (int o = 0; o < 10; ++o) acc[o] = fmaf(f, w[o], acc[o]);
    }
    if (lane < 16) {
      float f = statics[(size_t)b * 16 + lane];
      const float* w = W1 + (384 + lane) * 10;
#pragma unroll
      for (int o = 0; o < 10; ++o) acc[o] = fmaf(f, w[o], acc[o]);
    }
#pragma unroll
    for (int o = 0; o < 10; ++o) {
#pragma unroll
      for (int d = 1; d < 64; d <<= 1) acc[o] += __shfl_xor(acc[o], d, 64);
    }
    if (lane == 0) {
      float o0 = b2[0], o1 = b2[1];
#pragma unroll
      for (int o = 0; o < 10; ++o) {
        float a = fmaxf(acc[o] + b1[o], 0.f);
        o0 = fmaf(a, W2[o * 2 + 0], o0);
        o1 = fmaf(a, W2[o * 2 + 1], o1);
      }
      out[(size_t)b * 2 + 0] = o0;
      out[(size_t)b * 2 + 1] = o1;
    }
  }
}

extern "C" void kernel_launch(void* const* d_in, const int* in_sizes, int n_in,
                              void* d_out, int out_size, void* d_ws, size_t ws_size,
                              hipStream_t stream) {
  const float* x       = (const float*)d_in[0];
  const float* statics = (const float*)d_in[1];
  const float* maskp   = (const float*)d_in[2];
  const float* delta   = (const float*)d_in[3];
  const float* xlast   = (const float*)d_in[4];
  const float* xmean   = (const float*)d_in[5];
  const float* wdg     = (const float*)d_in[6];
  const float* bdg     = (const float*)d_in[7];
  const float* Wk      = (const float*)d_in[8];
  const float* Wv      = (const float*)d_in[9];
  const float* Wq      = (const float*)d_in[10];
  const float* Wih     = (const float*)d_in[11];
  const float* Whh     = (const float*)d_in[12];
  const float* bih     = (const float*)d_in[13];
  const float* bhh     = (const float*)d_in[14];
  const float* Wqc     = (const float*)d_in[15];
  const float* Wkc     = (const float*)d_in[16];
  const float* Wvc     = (const float*)d_in[17];
  const float* W1      = (const float*)d_in[18];
  const float* b1      = (const float*)d_in[19];
  const float* W2      = (const float*)d_in[20];
  const float* b2      = (const float*)d_in[21];
  float* ws = (float*)d_ws;  // needs 299008 floats = 1.196 MB

  wcombT_kernel<<<1152, 64, 0, stream>>>(Wv, Wih, ws);
  prep_transpose<<<880, 256, 0, stream>>>(Whh, Wq, Wk, Wqc, Wkc, Wvc, ws);
  rims_kernel<<<512, 512, 0, stream>>>(x, statics, maskp, delta, xlast, xmean,
                                       wdg, bdg, bih, bhh, W1, b1, W2, b2,
                                       ws, (float*)d_out);
}

// Round 4
// 1691.651 us; speedup vs baseline: 2.5513x; 2.5513x over previous
//
#include <hip/hip_runtime.h>
#include <math.h>

// dims (hardcoded per reference)
#define T_STEPS 50
#define BB 8   // batch rows per block; grid = 2048/8 = 256 blocks = 1 per CU
// Block = 1024 threads (16 waves). Single-block residency guarantees 16 waves/CU
// (multi-block co-scheduling requires VGPR<=64 on this HW -- R2/R3 evidence).

__device__ __forceinline__ void fma4(float4& a, const float4 v, const float s) {
  a.x = fmaf(v.x, s, a.x); a.y = fmaf(v.y, s, a.y);
  a.z = fmaf(v.z, s, a.z); a.w = fmaf(v.w, s, a.w);
}
__device__ __forceinline__ float sigmoidf_(float x) { return 1.0f / (1.0f + __expf(-x)); }
__device__ __forceinline__ float tanhf_(float x) {
  float ax = fabsf(x);
  float e = __expf(-2.0f * ax);
  float t = (1.0f - e) / (1.0f + e);
  return copysignf(t, x);
}

// Wcomb[r][f][g] = sum_v Wv[f][v] * Wih[r][v][g]  : [6][64][192] row-major
__global__ void wcomb_kernel(const float* __restrict__ Wv, const float* __restrict__ Wih,
                             float* __restrict__ Wc) {
  int g = threadIdx.x;          // 0..191
  int f = blockIdx.x & 63;      // 0..63
  int r = blockIdx.x >> 6;      // 0..5
  float acc = 0.f;
#pragma unroll 8
  for (int v = 0; v < 128; ++v)
    acc = fmaf(Wv[f * 128 + v], Wih[(r * 128 + v) * 192 + g], acc);
  Wc[(r * 64 + f) * 192 + g] = acc;
}

__global__ __launch_bounds__(1024, 1) void rims_kernel(
    const float* __restrict__ x, const float* __restrict__ statics,
    const float* __restrict__ maskp, const float* __restrict__ delta,
    const float* __restrict__ xlast, const float* __restrict__ xmean,
    const float* __restrict__ wdgp, const float* __restrict__ bdgp,
    const float* __restrict__ Wk, const float* __restrict__ Wq,
    const float* __restrict__ Whh, const float* __restrict__ bih,
    const float* __restrict__ bhh, const float* __restrict__ Wqc,
    const float* __restrict__ Wkc, const float* __restrict__ Wvc,
    const float* __restrict__ W1, const float* __restrict__ b1,
    const float* __restrict__ W2, const float* __restrict__ b2,
    const float* __restrict__ Wcomb, float* __restrict__ out) {
  // transposed activation tiles: [k][row] -> aligned float4-of-rows broadcast reads
  __shared__ float xh_T[64][8];
  __shared__ float h_T[6][64][8];
  __shared__ float hn_T[6][64][8];
  // GEMM outputs row-major [..][row][col]: lane-consecutive access, conflict-free
  __shared__ float K0_R[8][64];
  __shared__ float Q_R[6][8][64];
  __shared__ float qc_R[6][8][128];
  __shared__ float kc_R[6][8][128];
  __shared__ float vc_R[6][8][64];
  __shared__ float p0_l[8][6];
  __shared__ float act_l[8][6];

  const int tid = threadIdx.x;
  const int wave = tid >> 6;   // 0..15
  const int lane = tid & 63;
  const int b0 = blockIdx.x * BB;

  for (int i = tid; i < 6 * 64 * 8; i += 1024) (&h_T[0][0][0])[i] = 0.f;

  // X-phase constants (waves 0..7 own row = wave)
  const float wdg = wdgp[lane];
  const float bdg = bdgp[lane];
  const float xmv = xmean[(size_t)(b0 + (wave & 7)) * 64 + lane];
  // G1 biases hoisted: wave u<12 owns rim r = u>>1
  float bir = 0.f, biz = 0.f, bin = 0.f, bhr = 0.f, bhz = 0.f, bhn = 0.f;
  if (wave < 12) {
    const int r = wave >> 1;
    bir = bih[r * 192 + lane]; biz = bih[r * 192 + 64 + lane];
    bin = bih[r * 192 + 128 + lane];
    bhr = bhh[r * 192 + lane]; bhz = bhh[r * 192 + 64 + lane];
    bhn = bhh[r * 192 + 128 + lane];
  }
  __syncthreads();

  for (int t = 0; t < T_STEPS; ++t) {
    // ---------------- X: GRU-D decay / imputation (waves 0..7, row = wave)
    if (wave < 8) {
      size_t off = ((size_t)(b0 + wave) * T_STEPS + t) * 64 + lane;
      float xt = x[off], mt = maskp[off], dt = delta[off], xl = xlast[off];
      float gm = __expf(-fmaxf(fmaf(dt, wdg, bdg), 0.f));
      xh_T[lane][wave] = mt * xt + (1.f - mt) * (gm * xl + (1.f - gm) * xmv);
    }
    __syncthreads();
    // ---------------- G0: 14 units = (proj 0..6) x (row-quad 0..1); proj0=K0, 1..6=Q[r]
    if (wave < 14) {
      const int p = wave >> 1, q = wave & 1;
      const float* W = (p == 0) ? Wk : (Wq + (p - 1) * 4096);   // [64 in][64 out]
      const float(*src)[8] = (p == 0) ? xh_T : h_T[p - 1];
      float4 acc = {0, 0, 0, 0};
#pragma unroll 8
      for (int k = 0; k < 64; ++k) {
        float w = W[k * 64 + lane];                 // coalesced b32
        float4 a = *(const float4*)&src[k][q * 4];  // broadcast b128
        fma4(acc, a, w);
      }
      if (p == 0) {
        K0_R[q * 4 + 0][lane] = acc.x; K0_R[q * 4 + 1][lane] = acc.y;
        K0_R[q * 4 + 2][lane] = acc.z; K0_R[q * 4 + 3][lane] = acc.w;
      } else {
        float(*Qr)[64] = Q_R[p - 1];
        Qr[q * 4 + 0][lane] = acc.x; Qr[q * 4 + 1][lane] = acc.y;
        Qr[q * 4 + 2][lane] = acc.z; Qr[q * 4 + 3][lane] = acc.w;
      }
    }
    __syncthreads();
    // ---------------- R: logits, p0, top-4 mask (waves 0..7, row = wave)
    if (wave < 8) {
      const int row = wave;
      float k0 = K0_R[row][lane];
      float logit[6];
#pragma unroll
      for (int r = 0; r < 6; ++r) {
        float p = Q_R[r][row][lane] * k0;
#pragma unroll
        for (int d = 1; d < 64; d <<= 1) p += __shfl_xor(p, d, 64);
        logit[r] = p * 0.125f;  // 1/sqrt(KS)
      }
      if (lane == 0) {
#pragma unroll
        for (int r = 0; r < 6; ++r) {
          int rank = 0;
#pragma unroll
          for (int r2 = 0; r2 < 6; ++r2)
            rank += (logit[r2] > logit[r]) || (logit[r2] == logit[r] && r2 < r);
          p0_l[row][r] = sigmoidf_(logit[r]);   // softmax([l,0])[0]
          act_l[row][r] = (rank < 4) ? 1.f : 0.f;
        }
      }
    }
    __syncthreads();
    // ---------------- G1: 12 units = (rim 0..5) x (row-quad 0..1)
    if (wave < 12) {
      const int r = wave >> 1, q = wave & 1;
      const float* Wc = Wcomb + r * 12288;   // [64][192]
      const float* Wh = Whh + r * 12288;     // [64][192]
      float4 ur = {0,0,0,0}, uz = {0,0,0,0}, un = {0,0,0,0};
      float4 gr = {0,0,0,0}, gz = {0,0,0,0}, gn = {0,0,0,0};
#pragma unroll 4
      for (int k = 0; k < 64; ++k) {
        float w0 = Wc[k * 192 + lane], w1 = Wc[k * 192 + 64 + lane],
              w2 = Wc[k * 192 + 128 + lane];
        float v0 = Wh[k * 192 + lane], v1 = Wh[k * 192 + 64 + lane],
              v2 = Wh[k * 192 + 128 + lane];
        float4 xv = *(const float4*)&xh_T[k][q * 4];
        float4 hv = *(const float4*)&h_T[r][k][q * 4];
        fma4(ur, xv, w0); fma4(uz, xv, w1); fma4(un, xv, w2);
        fma4(gr, hv, v0); fma4(gz, hv, v1); fma4(gn, hv, v2);
      }
      float4 hold = *(const float4*)&h_T[r][lane][q * 4];
      auto gru1 = [&](float p0v, float u0, float u1, float u2, float g0, float g1,
                      float g2, float holdv) -> float {
        float rg = sigmoidf_(fmaf(p0v, u0, bir) + g0 + bhr);
        float zg = sigmoidf_(fmaf(p0v, u1, biz) + g1 + bhz);
        float ng = tanhf_(fmaf(p0v, u2, bin) + rg * (g2 + bhn));
        return (1.f - zg) * ng + zg * holdv;
      };
      float4 hn;
      hn.x = gru1(p0_l[q * 4 + 0][r], ur.x, uz.x, un.x, gr.x, gz.x, gn.x, hold.x);
      hn.y = gru1(p0_l[q * 4 + 1][r], ur.y, uz.y, un.y, gr.y, gz.y, gn.y, hold.y);
      hn.z = gru1(p0_l[q * 4 + 2][r], ur.z, uz.z, un.z, gr.z, gz.z, gn.z, hold.z);
      hn.w = gru1(p0_l[q * 4 + 3][r], ur.w, uz.w, un.w, gr.w, gz.w, gn.w, hold.w);
      *(float4*)&hn_T[r][lane][q * 4] = hn;
    }
    __syncthreads();
    // ---------------- C1: 36 units = {qc,kc} x (rim x quad) + vc x (rim x quad)
    for (int u = wave; u < 36; u += 16) {
      if (u < 24) {
        const int v = (u < 12) ? u : (u - 12);
        const int r = v >> 1, q = v & 1;
        const float* W = ((u < 12) ? Wqc : Wkc) + r * 8192;   // [64][128]
        float4 a0 = {0,0,0,0}, a1 = {0,0,0,0};
#pragma unroll 4
        for (int k = 0; k < 64; ++k) {
          float w0 = W[k * 128 + lane], w1 = W[k * 128 + 64 + lane];
          float4 a = *(const float4*)&hn_T[r][k][q * 4];
          fma4(a0, a, w0); fma4(a1, a, w1);
        }
        float(*dst)[128] = (u < 12) ? qc_R[r] : kc_R[r];
        dst[q * 4 + 0][lane] = a0.x; dst[q * 4 + 1][lane] = a0.y;
        dst[q * 4 + 2][lane] = a0.z; dst[q * 4 + 3][lane] = a0.w;
        dst[q * 4 + 0][64 + lane] = a1.x; dst[q * 4 + 1][64 + lane] = a1.y;
        dst[q * 4 + 2][64 + lane] = a1.z; dst[q * 4 + 3][64 + lane] = a1.w;
      } else {
        const int v = u - 24;
        const int r = v >> 1, q = v & 1;
        const float* W = Wvc + r * 4096;   // [64][64]
        float4 a0 = {0,0,0,0};
#pragma unroll 4
        for (int k = 0; k < 64; ++k) {
          float w = W[k * 64 + lane];
          float4 a = *(const float4*)&hn_T[r][k][q * 4];
          fma4(a0, a, w);
        }
        vc_R[r][q * 4 + 0][lane] = a0.x; vc_R[r][q * 4 + 1][lane] = a0.y;
        vc_R[r][q * 4 + 2][lane] = a0.z; vc_R[r][q * 4 + 3][lane] = a0.w;
      }
    }
    __syncthreads();
    // ---------------- C2: comm attention + state update; 16 units = (row, rim-half)
    {
      const int row = wave >> 1;
      const int half = wave & 1;
      float kcA[6], kcB[6], vcv[6];
#pragma unroll
      for (int s = 0; s < 6; ++s) {
        kcA[s] = kc_R[s][row][lane];
        kcB[s] = kc_R[s][row][64 + lane];
        vcv[s] = vc_R[s][row][lane];
      }
      const int cOut = lane >> 4;            // output head for this lane's comm col
      const int srcLane = (cOut & 1) << 5;   // lane holding that head's reduced score
      const float inv_sq = 0.17677669529663687f;  // 1/sqrt(QC)
#pragma unroll
      for (int jr = 0; jr < 3; ++jr) {
        const int rr = half * 3 + jr;
        float qA = qc_R[rr][row][lane], qB = qc_R[rr][row][64 + lane];
        float sL[6], sH[6];
#pragma unroll
        for (int s = 0; s < 6; ++s) {
          float p = qA * kcA[s];
          p += __shfl_xor(p, 1, 64); p += __shfl_xor(p, 2, 64); p += __shfl_xor(p, 4, 64);
          p += __shfl_xor(p, 8, 64); p += __shfl_xor(p, 16, 64);
          sL[s] = p * inv_sq;   // head 0 (lanes 0-31) / head 1 (lanes 32-63)
          float q = qB * kcB[s];
          q += __shfl_xor(q, 1, 64); q += __shfl_xor(q, 2, 64); q += __shfl_xor(q, 4, 64);
          q += __shfl_xor(q, 8, 64); q += __shfl_xor(q, 16, 64);
          sH[s] = q * inv_sq;   // heads 2 / 3
        }
        float mL = sL[0], mH = sH[0];
#pragma unroll
        for (int s = 1; s < 6; ++s) { mL = fmaxf(mL, sL[s]); mH = fmaxf(mH, sH[s]); }
        float sumL = 0.f, sumH = 0.f;
#pragma unroll
        for (int s = 0; s < 6; ++s) {
          sL[s] = __expf(sL[s] - mL); sumL += sL[s];
          sH[s] = __expf(sH[s] - mH); sumH += sH[s];
        }
        float rLn = 1.f / sumL, rHn = 1.f / sumH;
        float comm = 0.f;
#pragma unroll
        for (int s = 0; s < 6; ++s) {
          float tL = __shfl(sL[s] * rLn, srcLane, 64);
          float tH = __shfl(sH[s] * rHn, srcLane, 64);
          float cp = (cOut < 2) ? tL : tH;
          comm = fmaf(cp, vcv[s], comm);
        }
        float mk = act_l[row][rr];
        float hnv = hn_T[rr][lane][row];
        float hov = h_T[rr][lane][row];
        h_T[rr][lane][row] = (mk > 0.5f) ? (hnv + comm) : hov;
      }
    }
    __syncthreads();
  }  // t

  // ---------------- final MLP head (waves 0..7, row = wave)
  if (wave < 8) {
    const int b = b0 + wave;
    float acc[10];
#pragma unroll
    for (int o = 0; o < 10; ++o) acc[o] = 0.f;
#pragma unroll
    for (int ii = 0; ii < 6; ++ii) {
      float f = h_T[ii][lane][wave];
      const float* w = W1 + (ii * 64 + lane) * 10;
#pragma unroll
      for (int o = 0; o < 10; ++o) acc[o] = fmaf(f, w[o], acc[o]);
    }
    if (lane < 16) {
      float f = statics[(size_t)b * 16 + lane];
      const float* w = W1 + (384 + lane) * 10;
#pragma unroll
      for (int o = 0; o < 10; ++o) acc[o] = fmaf(f, w[o], acc[o]);
    }
#pragma unroll
    for (int o = 0; o < 10; ++o) {
#pragma unroll
      for (int d = 1; d < 64; d <<= 1) acc[o] += __shfl_xor(acc[o], d, 64);
    }
    if (lane == 0) {
      float o0 = b2[0], o1 = b2[1];
#pragma unroll
      for (int o = 0; o < 10; ++o) {
        float a = fmaxf(acc[o] + b1[o], 0.f);
        o0 = fmaf(a, W2[o * 2 + 0], o0);
        o1 = fmaf(a, W2[o * 2 + 1], o1);
      }
      out[(size_t)b * 2 + 0] = o0;
      out[(size_t)b * 2 + 1] = o1;
    }
  }
}

extern "C" void kernel_launch(void* const* d_in, const int* in_sizes, int n_in,
                              void* d_out, int out_size, void* d_ws, size_t ws_size,
                              hipStream_t stream) {
  const float* x       = (const float*)d_in[0];
  const float* statics = (const float*)d_in[1];
  const float* maskp   = (const float*)d_in[2];
  const float* delta   = (const float*)d_in[3];
  const float* xlast   = (const float*)d_in[4];
  const float* xmean   = (const float*)d_in[5];
  const float* wdg     = (const float*)d_in[6];
  const float* bdg     = (const float*)d_in[7];
  const float* Wk      = (const float*)d_in[8];
  const float* Wv      = (const float*)d_in[9];
  const float* Wq      = (const float*)d_in[10];
  const float* Wih     = (const float*)d_in[11];
  const float* Whh     = (const float*)d_in[12];
  const float* bih     = (const float*)d_in[13];
  const float* bhh     = (const float*)d_in[14];
  const float* Wqc     = (const float*)d_in[15];
  const float* Wkc     = (const float*)d_in[16];
  const float* Wvc     = (const float*)d_in[17];
  const float* W1      = (const float*)d_in[18];
  const float* b1      = (const float*)d_in[19];
  const float* W2      = (const float*)d_in[20];
  const float* b2      = (const float*)d_in[21];
  float* Wcomb = (float*)d_ws;  // 6*64*192 floats = 294912 B

  wcomb_kernel<<<384, 192, 0, stream>>>(Wv, Wih, Wcomb);
  rims_kernel<<<256, 1024, 0, stream>>>(x, statics, maskp, delta, xlast, xmean,
                                        wdg, bdg, Wk, Wq, Whh, bih, bhh,
                                        Wqc, Wkc, Wvc, W1, b1, W2, b2,
                                        Wcomb, (float*)d_out);
}